// Round 2
// baseline (311.934 us; speedup 1.0000x reference)
//
#include <hip/hip_runtime.h>

typedef unsigned short u16;
typedef unsigned int u32;
typedef __attribute__((ext_vector_type(8))) short short8;
typedef __attribute__((ext_vector_type(4))) float floatx4;

#define B_ 32
#define T_ 168
#define NH_ 32
#define NM_ 64
#define NN_ 96
#define E_ 384
#define HG_ 64
#define HL_ 128
#define FUT_ 24
#define SLOPE_ 0.01f

static __device__ __forceinline__ float b2f(u16 u) {
  u32 v = ((u32)u) << 16;
  return __builtin_bit_cast(float, v);
}
static __device__ __forceinline__ u16 f2bf(float f) {
  u32 x = __builtin_bit_cast(u32, f);
  u32 r = (x + 0x7fffu + ((x >> 16) & 1u)) >> 16;
  return (u16)r;
}
static __device__ __forceinline__ float fexp2(float x) { return __builtin_amdgcn_exp2f(x); }
static __device__ __forceinline__ float frcp(float x) { return __builtin_amdgcn_rcpf(x); }
static __device__ __forceinline__ float sigm(float x) {
  return frcp(1.0f + fexp2(-1.4426950408889634f * x));
}
static __device__ __forceinline__ float tanh_fast(float x) {
  // tanh(x) = 1 - 2/(exp(2x)+1), exp(2x) = 2^(x*2/ln2)
  return 1.0f - 2.0f * frcp(1.0f + fexp2(2.8853900817779268f * x));
}
static __device__ __forceinline__ float sel4(floatx4 v, int r) {
  float m0 = (r & 1) ? v[1] : v[0];
  float m1 = (r & 1) ? v[3] : v[2];
  return (r & 2) ? m1 : m0;
}
static __device__ __forceinline__ float lrelu(float x) {
  return fmaxf(x, SLOPE_ * x);  // valid for slope < 1
}

// dtype-agnostic scalar load: f32 flag selects float32 vs bf16 storage
static __device__ __forceinline__ float ldf(const void* p, size_t i, bool f32) {
  return f32 ? ((const float*)p)[i] : b2f(((const u16*)p)[i]);
}
// dtype-agnostic 8-consecutive-element load -> bf16 short8 fragment
static __device__ __forceinline__ short8 ld8(const void* p, size_t i, bool f32) {
  short8 r;
  if (f32) {
    const float* q = (const float*)p + i;
#pragma unroll
    for (int j = 0; j < 8; j++) r[j] = (short)f2bf(q[j]);
  } else {
    r = *(const short8*)((const u16*)p + i);
  }
  return r;
}

// ---------------- Phase 0: dtype probes -> flags in ws ----------------
// flags[0]: 1 = float tensors are fp32, 0 = bf16
// flags[1]: 1 = edge_index is int32, 0 = int64
__global__ void detect_kernel(const u16* __restrict__ dm, const int* __restrict__ eidx,
                              int* __restrict__ flags) {
  __shared__ int cnt;
  const int tid = threadIdx.x;  // 64
  if (tid == 0) cnt = 0;
  __syncthreads();
  // Even u16 words of data_meteo: bf16 storage -> genuine N(0,1) bf16 values
  // (exp field in [100,133] ~always). fp32 storage -> low mantissa halves
  // (~uniform bits, ~13% in range). Sample 512 words; threshold at 384.
  int c = 0;
  for (int i = tid; i < 512; i += 64) {
    u16 v = dm[2 * i];
    int e = (v >> 7) & 0xFF;
    if (e >= 100 && e <= 133) c++;
  }
  atomicAdd(&cnt, c);
  // int64-vs-int32: if int64, odd int32 words are all zero (values in [0,96)).
  int f2 = 0;
  for (int e = tid; e < E_; e += 64)
    if (eidx[2 * e + 1] != 0) f2 = 1;
  unsigned long long m = __ballot(f2 != 0);
  __syncthreads();
  if (tid == 0) {
    flags[0] = (cnt < 384) ? 1 : 0;
    flags[1] = (m != 0ull) ? 1 : 0;
  }
}

// ---------------- Phase 1: per-(b,t) graph aggregation -> agg[station] ----------------
// agg_ws layout: [station(32)][g = b*T + t (5376)] fp32
__global__ void gnn_agg_kernel(const void* __restrict__ dh, const void* __restrict__ dm,
                               const int* __restrict__ eidx, const int* __restrict__ flags,
                               float* __restrict__ agg_ws) {
  __shared__ float xs[NN_];
  __shared__ float agg[NH_];
  const int g = blockIdx.x;    // b*T + t
  const int tid = threadIdx.x; // 128 threads
  const bool f32 = flags[0] != 0;
  const bool is_i32 = flags[1] != 0;
  if (tid < NH_) agg[tid] = 0.0f;
  if (tid < NN_) {
    xs[tid] = (tid < NH_) ? ldf(dh, (size_t)g * NH_ + tid, f32)
                          : ldf(dm, (size_t)g * NM_ + (tid - NH_), f32);
  }
  __syncthreads();
  for (int e = tid; e < E_; e += 128) {
    int s = is_i32 ? eidx[e] : eidx[2 * e];
    int d = is_i32 ? eidx[E_ + e] : eidx[2 * E_ + 2 * e];
    if (d < NH_) atomicAdd(&agg[d], xs[s]);
  }
  __syncthreads();
  if (tid < NH_) agg_ws[tid * (B_ * T_) + g] = agg[tid];
}

// ---------------- Phase 2: fused GNN-feature build + per-station LSTM + head ----------
// Grid: 256 blocks = 32 stations x 8 batch-groups (4 batches each). 256 thr = 4 waves.
// Wave w owns gate rows {blk*128 + w*32 .. +32} for blk in {i,f,g,o}; weights K=192
// (64 x-part from Wih, 128 h-part from Whh) live in 48 short8 A-fragments in VGPRs.
__launch_bounds__(256, 1)
__global__ void lstm_kernel(const void* __restrict__ dh, const float* __restrict__ agg_ws,
                            const void* __restrict__ Wroot, const void* __restrict__ Wrel,
                            const void* __restrict__ bgnn, const void* __restrict__ Wih,
                            const void* __restrict__ Whh, const void* __restrict__ bih,
                            const void* __restrict__ bhh, const void* __restrict__ Wlin,
                            const void* __restrict__ blin, const int* __restrict__ flags,
                            void* __restrict__ out) {
  const int s = blockIdx.x & 31;
  const int bg = blockIdx.x >> 5;
  const int tid = threadIdx.x;
  const int w = tid >> 6;
  const int lane = tid & 63;
  const int cm = lane & 15;   // MFMA col (batch slot, 4 real + 3 duplicate groups)
  const int q = lane >> 4;    // quad
  const int b = cm & 3;       // local batch 0..3
  const int bglob = bg * 4 + b;
  const int rho = cm >> 2;    // duplicate-group role 0..3 -> handles acc element r=rho
  const bool f32 = flags[0] != 0;

  __shared__ __align__(16) u16 hbuf[2][4][136];  // double-buffered h, bf16, padded

  // ---- preload weight A-fragments: Af[tile=blk*2+t2][kk], kk 0..1 = Wih, 2..5 = Whh
  short8 Af[8][6];
#pragma unroll
  for (int blk = 0; blk < 4; blk++) {
#pragma unroll
    for (int t2 = 0; t2 < 2; t2++) {
      const int n = blk * 128 + w * 32 + t2 * 16 + cm;  // A row m = lane&15
      const int tl = blk * 2 + t2;
#pragma unroll
      for (int kk = 0; kk < 2; kk++)
        Af[tl][kk] = ld8(Wih, (size_t)(s * 512 + n) * 64 + kk * 32 + q * 8, f32);
#pragma unroll
      for (int kk = 0; kk < 4; kk++)
        Af[tl][2 + kk] = ld8(Whh, (size_t)(s * 512 + n) * 128 + kk * 32 + q * 8, f32);
    }
  }

  // ---- bias (bih+bhh) folded into acc init; layout matches C/D (row = q*4+r)
  floatx4 bias_init[8];
#pragma unroll
  for (int blk = 0; blk < 4; blk++) {
#pragma unroll
    for (int t2 = 0; t2 < 2; t2++) {
      const int tl = blk * 2 + t2;
#pragma unroll
      for (int r = 0; r < 4; r++) {
        const int n = blk * 128 + w * 32 + t2 * 16 + q * 4 + r;
        bias_init[tl][r] = ldf(bih, s * 512 + n, f32) + ldf(bhh, s * 512 + n, f32);
      }
    }
  }

  // ---- GNN linear coefficients for this lane's B-fragment k-slots
  float wr[16], wv[16], bgk[16];
#pragma unroll
  for (int kk = 0; kk < 2; kk++) {
#pragma unroll
    for (int jj = 0; jj < 8; jj++) {
      const int k = kk * 32 + q * 8 + jj;
      wr[kk * 8 + jj] = ldf(Wroot, k, f32);
      wv[kk * 8 + jj] = ldf(Wrel, k, f32);
      bgk[kk * 8 + jj] = ldf(bgnn, k, f32);
    }
  }

  // ---- zero h buffers (h0 = 0)
  for (int i = tid; i < 2 * 4 * 136; i += 256) ((u16*)hbuf)[i] = 0;
  float c0 = 0.0f, c1 = 0.0f;  // cell state for els (t2=0,r=rho) and (t2=1,r=rho)
  __syncthreads();

  const size_t dh_base = (size_t)bglob * T_ * NH_ + s;
  const int ag_base = s * (B_ * T_) + bglob * T_;

  for (int t = 0; t < T_; t++) {
    const int p = t & 1, pn = p ^ 1;
    // issue scalar loads early (consumed after the h-part MFMAs)
    const float xh = ldf(dh, dh_base + (size_t)t * NH_, f32);
    const float ag = agg_ws[ag_base + t];

    // h B-fragments from LDS: B[k = q*8+j][col = cm], col&3 real
    short8 Bh[4];
#pragma unroll
    for (int kk = 0; kk < 4; kk++)
      Bh[kk] = *(const short8*)(&hbuf[p][b][kk * 32 + q * 8]);

    floatx4 acc[8];
#pragma unroll
    for (int tl = 0; tl < 8; tl++) acc[tl] = bias_init[tl];

    // recurrent part: K = 128
#pragma unroll
    for (int kk = 0; kk < 4; kk++) {
#pragma unroll
      for (int tl = 0; tl < 8; tl++)
        acc[tl] = __builtin_amdgcn_mfma_f32_16x16x32_bf16(Af[tl][2 + kk], Bh[kk], acc[tl], 0, 0, 0);
    }

    // input part: build x-fragment on the fly from the two GNN scalars, K = 64
#pragma unroll
    for (int kk = 0; kk < 2; kk++) {
      short8 Bx;
#pragma unroll
      for (int jj = 0; jj < 8; jj++) {
        float xv = xh * wr[kk * 8 + jj] + ag * wv[kk * 8 + jj] + bgk[kk * 8 + jj];
        Bx[jj] = (short)f2bf(lrelu(xv));
      }
#pragma unroll
      for (int tl = 0; tl < 8; tl++)
        acc[tl] = __builtin_amdgcn_mfma_f32_16x16x32_bf16(Af[tl][kk], Bx, acc[tl], 0, 0, 0);
    }

    // activations: duplicate col-groups split the 8 per-lane elements 2-each (r = rho)
#pragma unroll
    for (int t2 = 0; t2 < 2; t2++) {
      const float gi = sel4(acc[0 + t2], rho);
      const float gf = sel4(acc[2 + t2], rho);
      const float gg = sel4(acc[4 + t2], rho);
      const float go = sel4(acc[6 + t2], rho);
      float& c = (t2 == 0) ? c0 : c1;
      c = sigm(gf) * c + sigm(gi) * tanh_fast(gg);
      const float hh = sigm(go) * tanh_fast(c);
      const int j = w * 32 + t2 * 16 + q * 4 + rho;
      hbuf[pn][b][j] = f2bf(hh);
    }
    __syncthreads();
  }

  // ---- head: pred[bglob][s][f] = lrelu(hT . Wlin[f] + blin[f]); final h is in hbuf[0]
  if (tid < 4 * FUT_) {
    const int bb = tid / FUT_;
    const int f = tid % FUT_;
    float accv = ldf(blin, f, f32);
#pragma unroll 4
    for (int k = 0; k < HL_; k++) accv += b2f(hbuf[0][bb][k]) * ldf(Wlin, f * HL_ + k, f32);
    const size_t oidx = ((size_t)(bg * 4 + bb) * NH_ + s) * FUT_ + f;
    const float ov = lrelu(accv);
    if (f32) ((float*)out)[oidx] = ov;
    else ((u16*)out)[oidx] = f2bf(ov);
  }
}

extern "C" void kernel_launch(void* const* d_in, const int* in_sizes, int n_in,
                              void* d_out, int out_size, void* d_ws, size_t ws_size,
                              hipStream_t stream) {
  const void* dm = d_in[0];               // data_meteo  [B,T,64,1]
  const void* dh = d_in[1];               // data_hydro  [B,T,32,1]
  const int* eidx = (const int*)d_in[2];  // edge_index  [2,384]
  const void* Wroot = d_in[3];            // [64,1]
  const void* Wrel = d_in[4];             // [64,1]
  const void* bgnn = d_in[5];             // [64]
  const void* Wih = d_in[6];              // [32,512,64]
  const void* Whh = d_in[7];              // [32,512,128]
  const void* bih = d_in[8];              // [32,512]
  const void* bhh = d_in[9];              // [32,512]
  const void* Wlin = d_in[10];            // [24,128]
  const void* blin = d_in[11];            // [24]

  int* flags = (int*)d_ws;                              // 64 B flag area
  float* agg_ws = (float*)((char*)d_ws + 64);           // [32][5376] fp32 = 688 KB

  detect_kernel<<<1, 64, 0, stream>>>((const u16*)dm, eidx, flags);
  gnn_agg_kernel<<<B_ * T_, 128, 0, stream>>>(dh, dm, eidx, flags, agg_ws);
  lstm_kernel<<<256, 256, 0, stream>>>(dh, agg_ws, Wroot, Wrel, bgnn, Wih, Whh,
                                       bih, bhh, Wlin, blin, flags, d_out);
}

// Round 3
// 200.597 us; speedup vs baseline: 1.5550x; 1.5550x over previous
//
#include <hip/hip_runtime.h>

typedef unsigned short u16;
typedef unsigned int u32;
typedef __attribute__((ext_vector_type(8))) short short8;
typedef __attribute__((ext_vector_type(4))) float floatx4;
typedef __attribute__((ext_vector_type(4))) float float4v;

#define B_ 32
#define T_ 168
#define NH_ 32
#define NM_ 64
#define E_ 384
#define HL_ 128
#define FUT_ 24
#define SLOPE_ 0.01f
#define XP_ 80   // xbuf stride per batch (u16): 80/8=10 ≡ 2 mod 8 -> 2-way max (free)
#define HP_ 144  // hbuf stride per batch (u16): 144/8=18 ≡ 2 mod 8 -> 2-way max (free)

static __device__ __forceinline__ float b2f(u16 u) {
  u32 v = ((u32)u) << 16;
  return __builtin_bit_cast(float, v);
}
static __device__ __forceinline__ u16 f2bf(float f) {
  u32 x = __builtin_bit_cast(u32, f);
  u32 r = (x + 0x7fffu + ((x >> 16) & 1u)) >> 16;
  return (u16)r;
}
static __device__ __forceinline__ float fexp2(float x) { return __builtin_amdgcn_exp2f(x); }
static __device__ __forceinline__ float frcp(float x) { return __builtin_amdgcn_rcpf(x); }
static __device__ __forceinline__ float sigm(float x) {
  return frcp(1.0f + fexp2(-1.4426950408889634f * x));
}
static __device__ __forceinline__ float tanh_fast(float x) {
  return 1.0f - 2.0f * frcp(1.0f + fexp2(2.8853900817779268f * x));
}
static __device__ __forceinline__ float sel4(floatx4 v, int r) {
  float m0 = (r & 1) ? v[1] : v[0];
  float m1 = (r & 1) ? v[3] : v[2];
  return (r & 2) ? m1 : m0;
}
static __device__ __forceinline__ float lrelu(float x) {
  return fmaxf(x, SLOPE_ * x);
}
// 8 consecutive fp32 -> bf16 short8 fragment
static __device__ __forceinline__ short8 ld8f(const float* p) {
  float4v a = *(const float4v*)p;
  float4v bq = *(const float4v*)(p + 4);
  short8 r;
#pragma unroll
  for (int j = 0; j < 4; j++) { r[j] = (short)f2bf(a[j]); r[4 + j] = (short)f2bf(bq[j]); }
  return r;
}

// Fully fused: per-WG graph aggregation + GNN feature precompute + per-station
// LSTM (MFMA, weights register-resident) + linear head.
// Grid: 256 WGs = 32 stations x 8 batch-groups (4 batches each). 512 thr = 8 waves
// (2 waves/SIMD). Wave w owns gate rows {blk*128 + w*16 .. +16} for blk in i,f,g,o.
__launch_bounds__(512, 2)
__global__ void fused_kernel(const float* __restrict__ dm, const float* __restrict__ dh,
                             const int* __restrict__ eidx,
                             const float* __restrict__ Wroot, const float* __restrict__ Wrel,
                             const float* __restrict__ bgnn,
                             const float* __restrict__ Wih, const float* __restrict__ Whh,
                             const float* __restrict__ bih, const float* __restrict__ bhh,
                             const float* __restrict__ Wlin, const float* __restrict__ blin,
                             float* __restrict__ out) {
  const int s = blockIdx.x & 31;
  const int bg = blockIdx.x >> 5;
  const int tid = threadIdx.x;
  const int w = tid >> 6;     // wave 0..7
  const int lane = tid & 63;
  const int cm = lane & 15;   // MFMA row/col index
  const int q = lane >> 4;    // quad
  const int b = cm & 3;       // real batch column (cols 4..15 duplicate 0..3)
  const int rho = cm >> 2;    // duplicate-group role: which acc element this lane activates

  __shared__ __align__(16) u16 xbuf[T_ * 4 * XP_];  // 107.5 KB precomputed GNN features (bf16)
  __shared__ __align__(16) u16 hbuf[2 * 4 * HP_];   // double-buffered h (bf16)
  __shared__ float xh_lds[4][T_];
  __shared__ float ag_lds[4][T_];
  __shared__ float wr_s[64], wv_s[64], bg_s[64];
  __shared__ int srcs[E_];
  __shared__ int nsrc, iflag;

  // ---- phase A: init
  if (tid == 0) { nsrc = 0; iflag = 0; }
  for (int i = tid; i < 2 * 4 * HP_; i += 512) hbuf[i] = 0;
  __syncthreads();

  // ---- phase B: int64-vs-int32 edge_index probe (odd words all zero => int64)
  {
    int odd = 0;
    for (int e = tid; e < E_; e += 512) odd |= eidx[2 * e + 1];
    if (odd) atomicOr(&iflag, 1);
  }
  __syncthreads();
  const bool i32 = iflag != 0;

  // ---- phase C: collect this station's in-edges; stage small tensors
  for (int e = tid; e < E_; e += 512) {
    int se = i32 ? eidx[e] : eidx[2 * e];
    int de = i32 ? eidx[E_ + e] : eidx[2 * E_ + 2 * e];
    if (de == s) { int i = atomicAdd(&nsrc, 1); srcs[i] = se; }
  }
  if (tid < 64) { wr_s[tid] = Wroot[tid]; wv_s[tid] = Wrel[tid]; bg_s[tid] = bgnn[tid]; }
  for (int i = tid; i < 4 * T_; i += 512) {
    int bb = i / T_, t = i % T_;
    xh_lds[bb][t] = dh[((size_t)(bg * 4 + bb) * T_ + t) * NH_ + s];
  }
  __syncthreads();

  // ---- phase D: per-(b,t) graph aggregation for this station (avg ~4 in-edges)
  const int ns = nsrc;
  for (int i = tid; i < 4 * T_; i += 512) {
    int bb = i / T_, t = i % T_;
    size_t gb = (size_t)(bg * 4 + bb) * T_ + t;
    float a = 0.f;
    for (int j = 0; j < ns; j++) {
      int sr = srcs[j];
      a += (sr < NH_) ? dh[gb * NH_ + sr] : dm[gb * NM_ + (sr - NH_)];
    }
    ag_lds[bb][t] = a;
  }
  __syncthreads();

  // ---- phase E: precompute all GNN features x[t][b][k] = lrelu(xh*Wroot + ag*Wrel + b)
  {
    const int k = tid & 63;
    const int bb = (tid >> 6) & 3;
    const int th = tid >> 8;  // 0/1: halves of T
    const float wrk = wr_s[k], wvk = wv_s[k], bgk = bg_s[k];
    for (int i = 0; i < T_ / 2; i++) {
      const int t = th * (T_ / 2) + i;
      const float xv = xh_lds[bb][t] * wrk + ag_lds[bb][t] * wvk + bgk;
      xbuf[t * (4 * XP_) + bb * XP_ + k] = f2bf(lrelu(xv));
    }
  }

  // ---- weight preload (register-resident, bf16 A-fragments): 4 tiles x 6 K-frags
  short8 Af[4][6];
  floatx4 bias_init[4];
#pragma unroll
  for (int blk = 0; blk < 4; blk++) {
    const int n = blk * 128 + w * 16 + cm;  // A row m = cm
#pragma unroll
    for (int kk = 0; kk < 2; kk++)
      Af[blk][kk] = ld8f(Wih + ((size_t)(s * 512 + n) * 64 + kk * 32 + q * 8));
#pragma unroll
    for (int kk = 0; kk < 4; kk++)
      Af[blk][2 + kk] = ld8f(Whh + ((size_t)(s * 512 + n) * 128 + kk * 32 + q * 8));
#pragma unroll
    for (int r = 0; r < 4; r++) {
      const int nb = blk * 128 + w * 16 + q * 4 + r;  // C/D row = q*4+r
      bias_init[blk][r] = bih[s * 512 + nb] + bhh[s * 512 + nb];
    }
  }
  __syncthreads();

  // ---- recurrent loop: 24 MFMAs/wave/step, 1 barrier/step
  float c = 0.0f;
#pragma unroll 2
  for (int t = 0; t < T_; t++) {
    const int p = t & 1, pn = p ^ 1;
    short8 Bh[4], Bx[2];
#pragma unroll
    for (int kk = 0; kk < 4; kk++)
      Bh[kk] = *(const short8*)(hbuf + p * (4 * HP_) + b * HP_ + kk * 32 + q * 8);
#pragma unroll
    for (int kk = 0; kk < 2; kk++)
      Bx[kk] = *(const short8*)(xbuf + t * (4 * XP_) + b * XP_ + kk * 32 + q * 8);

    floatx4 acc[4];
#pragma unroll
    for (int blk = 0; blk < 4; blk++) {
      acc[blk] = __builtin_amdgcn_mfma_f32_16x16x32_bf16(Af[blk][2], Bh[0], bias_init[blk], 0, 0, 0);
#pragma unroll
      for (int kk = 1; kk < 4; kk++)
        acc[blk] = __builtin_amdgcn_mfma_f32_16x16x32_bf16(Af[blk][2 + kk], Bh[kk], acc[blk], 0, 0, 0);
#pragma unroll
      for (int kk = 0; kk < 2; kk++)
        acc[blk] = __builtin_amdgcn_mfma_f32_16x16x32_bf16(Af[blk][kk], Bx[kk], acc[blk], 0, 0, 0);
    }

    // each lane activates exactly one h element: row = w*16 + q*4 + rho, col b
    const float gi = sel4(acc[0], rho);
    const float gf = sel4(acc[1], rho);
    const float gg = sel4(acc[2], rho);
    const float go = sel4(acc[3], rho);
    c = sigm(gf) * c + sigm(gi) * tanh_fast(gg);
    const float hh = sigm(go) * tanh_fast(c);
    hbuf[pn * (4 * HP_) + b * HP_ + w * 16 + q * 4 + rho] = f2bf(hh);
    __syncthreads();
  }

  // ---- head: out[b][s][f] = lrelu(hT . Wlin[f] + blin[f]); final h in hbuf[0]
  if (tid < 4 * FUT_) {
    const int bb = tid / FUT_;
    const int f = tid % FUT_;
    float a = blin[f];
#pragma unroll 8
    for (int k = 0; k < HL_; k++) a += b2f(hbuf[bb * HP_ + k]) * Wlin[f * HL_ + k];
    out[((size_t)(bg * 4 + bb) * NH_ + s) * FUT_ + f] = lrelu(a);
  }
}

extern "C" void kernel_launch(void* const* d_in, const int* in_sizes, int n_in,
                              void* d_out, int out_size, void* d_ws, size_t ws_size,
                              hipStream_t stream) {
  const float* dm = (const float*)d_in[0];    // data_meteo  [B,T,64,1] fp32
  const float* dh = (const float*)d_in[1];    // data_hydro  [B,T,32,1] fp32
  const int* eidx = (const int*)d_in[2];      // edge_index  [2,384] (i32 or i64, probed)
  const float* Wroot = (const float*)d_in[3]; // [64,1]
  const float* Wrel = (const float*)d_in[4];  // [64,1]
  const float* bgnn = (const float*)d_in[5];  // [64]
  const float* Wih = (const float*)d_in[6];   // [32,512,64]
  const float* Whh = (const float*)d_in[7];   // [32,512,128]
  const float* bih = (const float*)d_in[8];   // [32,512]
  const float* bhh = (const float*)d_in[9];   // [32,512]
  const float* Wlin = (const float*)d_in[10]; // [24,128]
  const float* blin = (const float*)d_in[11]; // [24]
  float* out = (float*)d_out;

  fused_kernel<<<256, 512, 0, stream>>>(dm, dh, eidx, Wroot, Wrel, bgnn, Wih, Whh,
                                        bih, bhh, Wlin, blin, out);
}